// Round 1
// baseline (832.619 us; speedup 1.0000x reference)
//
#include <hip/hip_runtime.h>

#define NN 50000
#define EE 800000
#define DD 64
#define GG 512
#define HIDD 64
#define D2 128

// ---------------- init: deg=1 (self-loop), pooled/cnt = 0 ----------------
__global__ void k_init(float* __restrict__ deg, float* __restrict__ pooled,
                       float* __restrict__ cnt) {
    int i = blockIdx.x * blockDim.x + threadIdx.x;
    if (i < NN) deg[i] = 1.0f;          // self-loop contributes 1 to in-degree
    if (i < GG * D2) pooled[i] = 0.0f;
    if (i < GG) cnt[i] = 0.0f;
}

// ---------------- in-degree count over edges ----------------
__global__ void k_degree(const int* __restrict__ dst, float* __restrict__ deg) {
    int e = blockIdx.x * blockDim.x + threadIdx.x;
    if (e < EE) atomicAdd(&deg[dst[e]], 1.0f);
}

// ---------------- GEMM1: t1s[i] = (x@W1)[i] * dinv[i]; acc1 = t1s (self-loop) ---
__global__ __launch_bounds__(256) void k_gemm1(const float* __restrict__ x,
        const float* __restrict__ W1, const float* __restrict__ deg,
        float* __restrict__ t1s, float* __restrict__ acc1) {
    __shared__ float w1s[DD][DD];   // 16 KB
    __shared__ float xs[4][DD];
    int tid = threadIdx.x;
    int col = tid & 63, rl = tid >> 6;
    #pragma unroll
    for (int i = 0; i < 16; ++i) {
        int idx = tid + i * 256;
        w1s[idx >> 6][idx & 63] = W1[idx];
    }
    int row0 = blockIdx.x * 64;
    for (int it = 0; it < 16; ++it) {
        int r = row0 + it * 4 + rl;
        __syncthreads();
        xs[rl][col] = (r < NN) ? x[r * DD + col] : 0.0f;
        __syncthreads();
        if (r < NN) {
            float s0 = 0.f, s1 = 0.f, s2 = 0.f, s3 = 0.f;
            #pragma unroll
            for (int k = 0; k < DD; k += 4) {
                s0 += xs[rl][k    ] * w1s[k    ][col];
                s1 += xs[rl][k + 1] * w1s[k + 1][col];
                s2 += xs[rl][k + 2] * w1s[k + 2][col];
                s3 += xs[rl][k + 3] * w1s[k + 3][col];
            }
            float v = (s0 + s1 + s2 + s3) * rsqrtf(deg[r]);
            t1s[r * DD + col] = v;
            acc1[r * DD + col] = v;
        }
    }
}

// ---------------- scatter layer 1: acc1[dst] += t1s[src] ----------------
__global__ void k_scatter1(const int* __restrict__ src, const int* __restrict__ dst,
                           const float* __restrict__ t1s, float* __restrict__ acc1) {
    unsigned gid = blockIdx.x * blockDim.x + threadIdx.x;
    int e = gid >> 6;
    int c = gid & 63;
    if (e < EE)
        atomicAdd(&acc1[dst[e] * DD + c], t1s[src[e] * DD + c]);
}

// -------- GEMM2: h1 = relu(dinv*acc1 + b1); t2s = (h1@W2)*dinv; acc2 = t2s ----
__global__ __launch_bounds__(256) void k_gemm2(const float* __restrict__ acc1,
        const float* __restrict__ W2, const float* __restrict__ b1,
        const float* __restrict__ deg,
        float* __restrict__ t2s, float* __restrict__ acc2) {
    __shared__ float w2s[DD][D2];   // 32 KB
    __shared__ float hs[2][DD];
    __shared__ float b1s[DD];
    int tid = threadIdx.x;
    #pragma unroll
    for (int i = 0; i < 32; ++i) {
        int idx = tid + i * 256;
        w2s[idx >> 7][idx & 127] = W2[idx];
    }
    if (tid < DD) b1s[tid] = b1[tid];
    int col = tid & 127, rl = tid >> 7;
    int row0 = blockIdx.x * 32;
    for (int it = 0; it < 16; ++it) {
        int r0 = row0 + it * 2;
        __syncthreads();
        if (tid < 128) {
            int rr = r0 + (tid >> 6);
            int k = tid & 63;
            float h = 0.0f;
            if (rr < NN)
                h = fmaxf(rsqrtf(deg[rr]) * acc1[rr * DD + k] + b1s[k], 0.0f);
            hs[tid >> 6][k] = h;
        }
        __syncthreads();
        int r = r0 + rl;
        if (r < NN) {
            float s0 = 0.f, s1 = 0.f, s2 = 0.f, s3 = 0.f;
            #pragma unroll
            for (int k = 0; k < DD; k += 4) {
                s0 += hs[rl][k    ] * w2s[k    ][col];
                s1 += hs[rl][k + 1] * w2s[k + 1][col];
                s2 += hs[rl][k + 2] * w2s[k + 2][col];
                s3 += hs[rl][k + 3] * w2s[k + 3][col];
            }
            float v = (s0 + s1 + s2 + s3) * rsqrtf(deg[r]);
            t2s[r * D2 + col] = v;
            acc2[r * D2 + col] = v;
        }
    }
}

// ---------------- scatter layer 2: acc2[dst] += t2s[src] ----------------
__global__ void k_scatter2(const int* __restrict__ src, const int* __restrict__ dst,
                           const float* __restrict__ t2s, float* __restrict__ acc2) {
    unsigned gid = blockIdx.x * blockDim.x + threadIdx.x;
    int e = gid >> 7;
    int c = gid & 127;
    if (e < EE)
        atomicAdd(&acc2[dst[e] * D2 + c], t2s[src[e] * D2 + c]);
}

// ------- pool: h2 = dinv*acc2 + b2; pooled[batch[i]] += h2; cnt[g] += 1 -------
__global__ void k_pool(const float* __restrict__ acc2, const float* __restrict__ deg,
                       const float* __restrict__ b2, const int* __restrict__ batch,
                       float* __restrict__ pooled, float* __restrict__ cnt) {
    unsigned gid = blockIdx.x * blockDim.x + threadIdx.x;
    int i = gid >> 7, c = gid & 127;
    if (i < NN) {
        float v = rsqrtf(deg[i]) * acc2[i * D2 + c] + b2[c];
        int g = batch[i];
        atomicAdd(&pooled[g * D2 + c], v);
        if (c == 0) atomicAdd(&cnt[g], 1.0f);
    }
}

// ---------------- final FC: out[g][j] = (pooled[g]/cnt) @ Wfc + bfc ----------
__global__ void k_final(const float* __restrict__ pooled, const float* __restrict__ cnt,
                        const float* __restrict__ Wfc, const float* __restrict__ bfc,
                        float* __restrict__ out) {
    int gid = blockIdx.x * blockDim.x + threadIdx.x;   // G*HID = 32768
    int g = gid >> 6, j = gid & 63;
    if (g < GG) {
        float inv = 1.0f / fmaxf(cnt[g], 1.0f);
        float s = 0.0f;
        #pragma unroll
        for (int k = 0; k < D2; ++k)
            s += pooled[g * D2 + k] * Wfc[k * HIDD + j];
        out[gid] = s * inv + bfc[j];
    }
}

extern "C" void kernel_launch(void* const* d_in, const int* in_sizes, int n_in,
                              void* d_out, int out_size, void* d_ws, size_t ws_size,
                              hipStream_t stream) {
    const float* x     = (const float*)d_in[0];
    const int*   ei    = (const int*)  d_in[1];   // [2, E] int32
    const int*   batch = (const int*)  d_in[2];   // [N]
    const float* W1    = (const float*)d_in[3];
    const float* b1    = (const float*)d_in[4];
    const float* W2    = (const float*)d_in[5];
    const float* b2    = (const float*)d_in[6];
    const float* Wfc   = (const float*)d_in[7];
    const float* bfc   = (const float*)d_in[8];
    float* out = (float*)d_out;

    const int* src = ei;        // edge_index[0]
    const int* dst = ei + EE;   // edge_index[1]

    // workspace layout (floats)
    float* ws   = (float*)d_ws;
    float* deg  = ws;                       // N        (padded to 50048)
    float* t1s  = ws + 50048;               // N*64
    float* acc1 = t1s + NN * DD;            // N*64
    float* t2s  = acc1 + NN * DD;           // N*128
    float* acc2 = t2s + NN * D2;            // N*128
    float* pooled = acc2 + NN * D2;         // G*128
    float* cnt  = pooled + GG * D2;         // G
    // total ~77.3 MB

    k_init<<<(GG * D2 + 255) / 256, 256, 0, stream>>>(deg, pooled, cnt);
    k_degree<<<(EE + 255) / 256, 256, 0, stream>>>(dst, deg);
    k_gemm1<<<(NN + 63) / 64, 256, 0, stream>>>(x, W1, deg, t1s, acc1);
    k_scatter1<<<(EE * DD) / 256, 256, 0, stream>>>(src, dst, t1s, acc1);
    k_gemm2<<<(NN + 31) / 32, 256, 0, stream>>>(acc1, W2, b1, deg, t2s, acc2);
    k_scatter2<<<(EE * D2) / 256, 256, 0, stream>>>(src, dst, t2s, acc2);
    k_pool<<<(NN * D2) / 256, 256, 0, stream>>>(acc2, deg, b2, batch, pooled, cnt);
    k_final<<<(GG * HIDD) / 256, 256, 0, stream>>>(pooled, cnt, Wfc, bfc, out);
}

// Round 6
// 460.211 us; speedup vs baseline: 1.8092x; 1.8092x over previous
//
#include <hip/hip_runtime.h>

#define NN 50000
#define EE 800000
#define DD 64
#define GG 512
#define HIDD 64
#define D2 128
#define NBLK 196          // ceil(NN/256)

// ---------------- zero: cnt_in[N], part[256], pooled, cnt ----------------
__global__ void k_zero(int* __restrict__ cnt_in, int* __restrict__ part,
                       float* __restrict__ pooled, float* __restrict__ cnt) {
    int i = blockIdx.x * blockDim.x + threadIdx.x;
    if (i < NN) cnt_in[i] = 0;
    if (i < 256) part[i] = 0;
    if (i < GG * D2) pooled[i] = 0.0f;
    if (i < GG) cnt[i] = 0.0f;
}

// ---------------- in-degree count over edges (int atomics) ----------------
__global__ void k_count(const int* __restrict__ dst, int* __restrict__ cnt_in) {
    int e = blockIdx.x * blockDim.x + threadIdx.x;
    if (e < EE) atomicAdd(&cnt_in[dst[e]], 1);
}

// ---------------- scan step 1: per-block sums ----------------
__global__ void k_partial(const int* __restrict__ cnt_in, int* __restrict__ part) {
    __shared__ int s[256];
    int t = threadIdx.x, i = blockIdx.x * 256 + t;
    s[t] = (i < NN) ? cnt_in[i] : 0;
    __syncthreads();
    for (int off = 128; off > 0; off >>= 1) {
        if (t < off) s[t] += s[t + off];
        __syncthreads();
    }
    if (t == 0) part[blockIdx.x] = s[0];
}

// ---------------- scan step 2: exclusive scan of 256 partials ----------------
__global__ void k_scanp(int* __restrict__ part) {
    __shared__ int s[256];
    int t = threadIdx.x;
    int v = part[t];
    s[t] = v;
    __syncthreads();
    for (int off = 1; off < 256; off <<= 1) {
        int add = (t >= off) ? s[t - off] : 0;
        __syncthreads();
        s[t] += add;
        __syncthreads();
    }
    part[t] = s[t] - v;     // exclusive
}

// ---------------- scan step 3: rowptr + cursor ----------------
__global__ void k_rowptr(const int* __restrict__ cnt_in, const int* __restrict__ part,
                         int* __restrict__ rowptr, int* __restrict__ cursor) {
    __shared__ int s[256];
    int t = threadIdx.x, i = blockIdx.x * 256 + t;
    int v = (i < NN) ? cnt_in[i] : 0;
    s[t] = v;
    __syncthreads();
    for (int off = 1; off < 256; off <<= 1) {
        int add = (t >= off) ? s[t - off] : 0;
        __syncthreads();
        s[t] += add;
        __syncthreads();
    }
    int excl = s[t] - v + part[blockIdx.x];
    if (i <= NN) rowptr[i] = excl;          // rowptr[NN] == EE
    if (i < NN) cursor[i] = excl;
}

// ---------------- CSR fill: csr_src[pos] = src ----------------
__global__ void k_fill(const int* __restrict__ src, const int* __restrict__ dst,
                       int* __restrict__ cursor, int* __restrict__ csr) {
    int e = blockIdx.x * blockDim.x + threadIdx.x;
    if (e < EE) {
        int pos = atomicAdd(&cursor[dst[e]], 1);
        csr[pos] = src[e];
    }
}

// -------- GEMM1: t1s[i] = (x@W1)[i] * dinv[i] ----------------
__global__ __launch_bounds__(256) void k_gemm1(const float* __restrict__ x,
        const float* __restrict__ W1, const int* __restrict__ cnt_in,
        float* __restrict__ t1s) {
    __shared__ float w1s[DD][DD];
    __shared__ float xs[4][DD];
    int tid = threadIdx.x;
    int col = tid & 63, rl = tid >> 6;
    #pragma unroll
    for (int i = 0; i < 16; ++i) {
        int idx = tid + i * 256;
        w1s[idx >> 6][idx & 63] = W1[idx];
    }
    int row0 = blockIdx.x * 64;
    for (int it = 0; it < 16; ++it) {
        int r = row0 + it * 4 + rl;
        __syncthreads();
        xs[rl][col] = (r < NN) ? x[r * DD + col] : 0.0f;
        __syncthreads();
        if (r < NN) {
            float s0 = 0.f, s1 = 0.f, s2 = 0.f, s3 = 0.f;
            #pragma unroll
            for (int k = 0; k < DD; k += 4) {
                s0 += xs[rl][k    ] * w1s[k    ][col];
                s1 += xs[rl][k + 1] * w1s[k + 1][col];
                s2 += xs[rl][k + 2] * w1s[k + 2][col];
                s3 += xs[rl][k + 3] * w1s[k + 3][col];
            }
            t1s[r * DD + col] = (s0 + s1 + s2 + s3) * rsqrtf((float)cnt_in[r] + 1.0f);
        }
    }
}

// -------- aggregate layer 1: acc1[i] = t1s[i] + sum_{src->i} t1s[src] --------
__global__ __launch_bounds__(256) void k_agg1(const int* __restrict__ rowptr,
        const int* __restrict__ csr, const float* __restrict__ t1s,
        float* __restrict__ acc1) {
    int wid = (blockIdx.x * blockDim.x + threadIdx.x) >> 6;
    int c = threadIdx.x & 63;
    if (wid >= NN) return;
    int beg = rowptr[wid], end = rowptr[wid + 1];
    float a0 = t1s[wid * DD + c];       // self-loop term
    float a1 = 0.f, a2 = 0.f, a3 = 0.f;
    int e = beg;
    for (; e + 4 <= end; e += 4) {
        int s0 = csr[e], s1 = csr[e + 1], s2 = csr[e + 2], s3 = csr[e + 3];
        a0 += t1s[s0 * DD + c];
        a1 += t1s[s1 * DD + c];
        a2 += t1s[s2 * DD + c];
        a3 += t1s[s3 * DD + c];
    }
    for (; e < end; ++e) a0 += t1s[csr[e] * DD + c];
    acc1[wid * DD + c] = (a0 + a1) + (a2 + a3);
}

// -------- GEMM2: h1 = relu(dinv*acc1 + b1); t2s = (h1@W2)*dinv ----
__global__ __launch_bounds__(256) void k_gemm2(const float* __restrict__ acc1,
        const float* __restrict__ W2, const float* __restrict__ b1,
        const int* __restrict__ cnt_in, float* __restrict__ t2s) {
    __shared__ float w2s[DD][D2];
    __shared__ float hs[2][DD];
    __shared__ float b1s[DD];
    int tid = threadIdx.x;
    #pragma unroll
    for (int i = 0; i < 32; ++i) {
        int idx = tid + i * 256;
        w2s[idx >> 7][idx & 127] = W2[idx];
    }
    if (tid < DD) b1s[tid] = b1[tid];
    int col = tid & 127, rl = tid >> 7;
    int row0 = blockIdx.x * 32;
    for (int it = 0; it < 16; ++it) {
        int r0 = row0 + it * 2;
        __syncthreads();
        if (tid < 128) {
            int rr = r0 + (tid >> 6);
            int k = tid & 63;
            float h = 0.0f;
            if (rr < NN)
                h = fmaxf(rsqrtf((float)cnt_in[rr] + 1.0f) * acc1[rr * DD + k] + b1s[k], 0.0f);
            hs[tid >> 6][k] = h;
        }
        __syncthreads();
        int r = r0 + rl;
        if (r < NN) {
            float s0 = 0.f, s1 = 0.f, s2 = 0.f, s3 = 0.f;
            #pragma unroll
            for (int k = 0; k < DD; k += 4) {
                s0 += hs[rl][k    ] * w2s[k    ][col];
                s1 += hs[rl][k + 1] * w2s[k + 1][col];
                s2 += hs[rl][k + 2] * w2s[k + 2][col];
                s3 += hs[rl][k + 3] * w2s[k + 3][col];
            }
            t2s[r * D2 + col] = (s0 + s1 + s2 + s3) * rsqrtf((float)cnt_in[r] + 1.0f);
        }
    }
}

// -------- aggregate layer 2 (float2 lanes): lane c handles channels 2c,2c+1 --
__global__ __launch_bounds__(256) void k_agg2(const int* __restrict__ rowptr,
        const int* __restrict__ csr, const float* __restrict__ t2s,
        float* __restrict__ acc2) {
    int wid = (blockIdx.x * blockDim.x + threadIdx.x) >> 6;
    int c = threadIdx.x & 63;
    if (wid >= NN) return;
    int beg = rowptr[wid], end = rowptr[wid + 1];
    float2 v = ((const float2*)&t2s[wid * D2])[c];   // self-loop term
    float a0 = v.x, b0 = v.y;
    float a1 = 0.f, b1 = 0.f, a2 = 0.f, b2 = 0.f, a3 = 0.f, b3 = 0.f;
    int e = beg;
    for (; e + 4 <= end; e += 4) {
        int s0 = csr[e], s1 = csr[e + 1], s2 = csr[e + 2], s3 = csr[e + 3];
        float2 u0 = ((const float2*)&t2s[s0 * D2])[c];
        float2 u1 = ((const float2*)&t2s[s1 * D2])[c];
        float2 u2 = ((const float2*)&t2s[s2 * D2])[c];
        float2 u3 = ((const float2*)&t2s[s3 * D2])[c];
        a0 += u0.x; b0 += u0.y;
        a1 += u1.x; b1 += u1.y;
        a2 += u2.x; b2 += u2.y;
        a3 += u3.x; b3 += u3.y;
    }
    for (; e < end; ++e) {
        float2 u = ((const float2*)&t2s[csr[e] * D2])[c];
        a0 += u.x; b0 += u.y;
    }
    float2 o;
    o.x = (a0 + a1) + (a2 + a3);
    o.y = (b0 + b1) + (b2 + b3);
    ((float2*)&acc2[wid * D2])[c] = o;
}

// ------- pool: h2 = dinv*acc2 + b2; pooled[batch[i]] += h2; cnt[g] += 1 -------
__global__ void k_pool(const float* __restrict__ acc2, const int* __restrict__ cnt_in,
                       const float* __restrict__ b2, const int* __restrict__ batch,
                       float* __restrict__ pooled, float* __restrict__ cnt) {
    unsigned gid = blockIdx.x * blockDim.x + threadIdx.x;
    int i = gid >> 7, c = gid & 127;
    if (i < NN) {
        float v = rsqrtf((float)cnt_in[i] + 1.0f) * acc2[i * D2 + c] + b2[c];
        int g = batch[i];
        atomicAdd(&pooled[g * D2 + c], v);
        if (c == 0) atomicAdd(&cnt[g], 1.0f);
    }
}

// ---------------- final FC ----------------
__global__ void k_final(const float* __restrict__ pooled, const float* __restrict__ cnt,
                        const float* __restrict__ Wfc, const float* __restrict__ bfc,
                        float* __restrict__ out) {
    int gid = blockIdx.x * blockDim.x + threadIdx.x;
    int g = gid >> 6, j = gid & 63;
    if (g < GG) {
        float inv = 1.0f / fmaxf(cnt[g], 1.0f);
        float s = 0.0f;
        #pragma unroll
        for (int k = 0; k < D2; ++k)
            s += pooled[g * D2 + k] * Wfc[k * HIDD + j];
        out[gid] = s * inv + bfc[j];
    }
}

extern "C" void kernel_launch(void* const* d_in, const int* in_sizes, int n_in,
                              void* d_out, int out_size, void* d_ws, size_t ws_size,
                              hipStream_t stream) {
    const float* x     = (const float*)d_in[0];
    const int*   ei    = (const int*)  d_in[1];
    const int*   batch = (const int*)  d_in[2];
    const float* W1    = (const float*)d_in[3];
    const float* b1    = (const float*)d_in[4];
    const float* W2    = (const float*)d_in[5];
    const float* b2    = (const float*)d_in[6];
    const float* Wfc   = (const float*)d_in[7];
    const float* bfc   = (const float*)d_in[8];
    float* out = (float*)d_out;

    const int* src = ei;
    const int* dst = ei + EE;

    // ---- workspace layout ----
    float* fws    = (float*)d_ws;
    float* t1s    = fws;                        // NN*DD
    float* acc1   = t1s + NN * DD;              // NN*DD
    float* acc2   = t1s;                        // aliases t1s+acc1 (both dead)
    float* t2s    = acc1 + NN * DD;             // NN*D2
    float* pooled = t2s + NN * D2;              // GG*D2
    float* cnt    = pooled + GG * D2;           // GG
    int*   iws    = (int*)(cnt + GG + 256);
    int*   cnt_in = iws;                        // NN
    int*   rowptr = cnt_in + 50048;             // NN+1
    int*   cursor = rowptr + 50304;             // NN
    int*   part   = cursor + 50048;             // 256
    int*   csr    = part + 256;                 // EE
    // total ≈ 55 MB

    k_zero  <<<(GG * D2 + 255) / 256, 256, 0, stream>>>(cnt_in, part, pooled, cnt);
    k_count <<<(EE + 255) / 256, 256, 0, stream>>>(dst, cnt_in);
    k_partial<<<NBLK, 256, 0, stream>>>(cnt_in, part);
    k_scanp <<<1, 256, 0, stream>>>(part);
    k_rowptr<<<NBLK, 256, 0, stream>>>(cnt_in, part, rowptr, cursor);
    k_fill  <<<(EE + 255) / 256, 256, 0, stream>>>(src, dst, cursor, csr);
    k_gemm1 <<<(NN + 63) / 64, 256, 0, stream>>>(x, W1, cnt_in, t1s);
    k_agg1  <<<(NN * 64 + 255) / 256, 256, 0, stream>>>(rowptr, csr, t1s, acc1);
    k_gemm2 <<<(NN + 31) / 32, 256, 0, stream>>>(acc1, W2, b1, cnt_in, t2s);
    k_agg2  <<<(NN * 64 + 255) / 256, 256, 0, stream>>>(rowptr, csr, t2s, acc2);
    k_pool  <<<(NN * D2 + 255) / 256, 256, 0, stream>>>(acc2, cnt_in, b2, batch, pooled, cnt);
    k_final <<<(GG * HIDD + 255) / 256, 256, 0, stream>>>(pooled, cnt, Wfc, bfc, out);
}

// Round 7
// 364.177 us; speedup vs baseline: 2.2863x; 1.2637x over previous
//
#include <hip/hip_runtime.h>

#define NN 50000
#define EE 800000
#define DD 64
#define GG 512
#define HIDD 64
#define D2 128
#define NBLK 196          // ceil(NN/256)

// ---------------- zero: cnt_in[N], part[256] ----------------
__global__ void k_zero(int* __restrict__ cnt_in, int* __restrict__ part) {
    int i = blockIdx.x * blockDim.x + threadIdx.x;
    if (i < NN) cnt_in[i] = 0;
    if (i < 256) part[i] = 0;
}

// ---------------- in-degree count over edges (int atomics) ----------------
__global__ void k_count(const int* __restrict__ dst, int* __restrict__ cnt_in) {
    int e = blockIdx.x * blockDim.x + threadIdx.x;
    if (e < EE) atomicAdd(&cnt_in[dst[e]], 1);
}

// ---------------- scan step 1: per-block sums ----------------
__global__ void k_partial(const int* __restrict__ cnt_in, int* __restrict__ part) {
    __shared__ int s[256];
    int t = threadIdx.x, i = blockIdx.x * 256 + t;
    s[t] = (i < NN) ? cnt_in[i] : 0;
    __syncthreads();
    for (int off = 128; off > 0; off >>= 1) {
        if (t < off) s[t] += s[t + off];
        __syncthreads();
    }
    if (t == 0) part[blockIdx.x] = s[0];
}

// ---------------- scan step 2: exclusive scan of 256 partials ----------------
__global__ void k_scanp(int* __restrict__ part) {
    __shared__ int s[256];
    int t = threadIdx.x;
    int v = part[t];
    s[t] = v;
    __syncthreads();
    for (int off = 1; off < 256; off <<= 1) {
        int add = (t >= off) ? s[t - off] : 0;
        __syncthreads();
        s[t] += add;
        __syncthreads();
    }
    part[t] = s[t] - v;     // exclusive
}

// ---------------- scan step 3: rowptr + cursor ----------------
__global__ void k_rowptr(const int* __restrict__ cnt_in, const int* __restrict__ part,
                         int* __restrict__ rowptr, int* __restrict__ cursor) {
    __shared__ int s[256];
    int t = threadIdx.x, i = blockIdx.x * 256 + t;
    int v = (i < NN) ? cnt_in[i] : 0;
    s[t] = v;
    __syncthreads();
    for (int off = 1; off < 256; off <<= 1) {
        int add = (t >= off) ? s[t - off] : 0;
        __syncthreads();
        s[t] += add;
        __syncthreads();
    }
    int excl = s[t] - v + part[blockIdx.x];
    if (i <= NN) rowptr[i] = excl;          // rowptr[NN] == EE
    if (i < NN) cursor[i] = excl;
}

// ---------------- CSR fill: csr_src[pos] = src ----------------
__global__ void k_fill(const int* __restrict__ src, const int* __restrict__ dst,
                       int* __restrict__ cursor, int* __restrict__ csr) {
    int e = blockIdx.x * blockDim.x + threadIdx.x;
    if (e < EE) {
        int pos = atomicAdd(&cursor[dst[e]], 1);
        csr[pos] = src[e];
    }
}

// -------- GEMM1: t1s[i] = (x@W1)[i] * dinv[i] ----------------
__global__ __launch_bounds__(256) void k_gemm1(const float* __restrict__ x,
        const float* __restrict__ W1, const int* __restrict__ cnt_in,
        float* __restrict__ t1s) {
    __shared__ float w1s[DD][DD];
    __shared__ float xs[4][DD];
    int tid = threadIdx.x;
    int col = tid & 63, rl = tid >> 6;
    #pragma unroll
    for (int i = 0; i < 16; ++i) {
        int idx = tid + i * 256;
        w1s[idx >> 6][idx & 63] = W1[idx];
    }
    int row0 = blockIdx.x * 64;
    for (int it = 0; it < 16; ++it) {
        int r = row0 + it * 4 + rl;
        __syncthreads();
        xs[rl][col] = (r < NN) ? x[r * DD + col] : 0.0f;
        __syncthreads();
        if (r < NN) {
            float s0 = 0.f, s1 = 0.f, s2 = 0.f, s3 = 0.f;
            #pragma unroll
            for (int k = 0; k < DD; k += 4) {
                s0 += xs[rl][k    ] * w1s[k    ][col];
                s1 += xs[rl][k + 1] * w1s[k + 1][col];
                s2 += xs[rl][k + 2] * w1s[k + 2][col];
                s3 += xs[rl][k + 3] * w1s[k + 3][col];
            }
            t1s[r * DD + col] = (s0 + s1 + s2 + s3) * rsqrtf((float)cnt_in[r] + 1.0f);
        }
    }
}

// -------- aggregate layer 1: acc1[i] = t1s[i] + sum_{src->i} t1s[src] --------
__global__ __launch_bounds__(256) void k_agg1(const int* __restrict__ rowptr,
        const int* __restrict__ csr, const float* __restrict__ t1s,
        float* __restrict__ acc1) {
    int wid = (blockIdx.x * blockDim.x + threadIdx.x) >> 6;
    int c = threadIdx.x & 63;
    if (wid >= NN) return;
    int beg = rowptr[wid], end = rowptr[wid + 1];
    float a0 = t1s[wid * DD + c];       // self-loop term
    float a1 = 0.f, a2 = 0.f, a3 = 0.f;
    int e = beg;
    for (; e + 4 <= end; e += 4) {
        int s0 = csr[e], s1 = csr[e + 1], s2 = csr[e + 2], s3 = csr[e + 3];
        a0 += t1s[s0 * DD + c];
        a1 += t1s[s1 * DD + c];
        a2 += t1s[s2 * DD + c];
        a3 += t1s[s3 * DD + c];
    }
    for (; e < end; ++e) a0 += t1s[csr[e] * DD + c];
    acc1[wid * DD + c] = (a0 + a1) + (a2 + a3);
}

// -------- GEMM2: h1 = relu(dinv*acc1 + b1); t2s = (h1@W2)*dinv ----
__global__ __launch_bounds__(256) void k_gemm2(const float* __restrict__ acc1,
        const float* __restrict__ W2, const float* __restrict__ b1,
        const int* __restrict__ cnt_in, float* __restrict__ t2s) {
    __shared__ float w2s[DD][D2];
    __shared__ float hs[2][DD];
    __shared__ float b1s[DD];
    int tid = threadIdx.x;
    #pragma unroll
    for (int i = 0; i < 32; ++i) {
        int idx = tid + i * 256;
        w2s[idx >> 7][idx & 127] = W2[idx];
    }
    if (tid < DD) b1s[tid] = b1[tid];
    int col = tid & 127, rl = tid >> 7;
    int row0 = blockIdx.x * 32;
    for (int it = 0; it < 16; ++it) {
        int r0 = row0 + it * 2;
        __syncthreads();
        if (tid < 128) {
            int rr = r0 + (tid >> 6);
            int k = tid & 63;
            float h = 0.0f;
            if (rr < NN)
                h = fmaxf(rsqrtf((float)cnt_in[rr] + 1.0f) * acc1[rr * DD + k] + b1s[k], 0.0f);
            hs[tid >> 6][k] = h;
        }
        __syncthreads();
        int r = r0 + rl;
        if (r < NN) {
            float s0 = 0.f, s1 = 0.f, s2 = 0.f, s3 = 0.f;
            #pragma unroll
            for (int k = 0; k < DD; k += 4) {
                s0 += hs[rl][k    ] * w2s[k    ][col];
                s1 += hs[rl][k + 1] * w2s[k + 1][col];
                s2 += hs[rl][k + 2] * w2s[k + 2][col];
                s3 += hs[rl][k + 3] * w2s[k + 3][col];
            }
            t2s[r * D2 + col] = (s0 + s1 + s2 + s3) * rsqrtf((float)cnt_in[r] + 1.0f);
        }
    }
}

// -------- aggregate layer 2 (float2 lanes): lane c handles channels 2c,2c+1 --
__global__ __launch_bounds__(256) void k_agg2(const int* __restrict__ rowptr,
        const int* __restrict__ csr, const float* __restrict__ t2s,
        float* __restrict__ acc2) {
    int wid = (blockIdx.x * blockDim.x + threadIdx.x) >> 6;
    int c = threadIdx.x & 63;
    if (wid >= NN) return;
    int beg = rowptr[wid], end = rowptr[wid + 1];
    float2 v = ((const float2*)&t2s[wid * D2])[c];   // self-loop term
    float a0 = v.x, b0 = v.y;
    float a1 = 0.f, b1 = 0.f, a2 = 0.f, b2 = 0.f, a3 = 0.f, b3 = 0.f;
    int e = beg;
    for (; e + 4 <= end; e += 4) {
        int s0 = csr[e], s1 = csr[e + 1], s2 = csr[e + 2], s3 = csr[e + 3];
        float2 u0 = ((const float2*)&t2s[s0 * D2])[c];
        float2 u1 = ((const float2*)&t2s[s1 * D2])[c];
        float2 u2 = ((const float2*)&t2s[s2 * D2])[c];
        float2 u3 = ((const float2*)&t2s[s3 * D2])[c];
        a0 += u0.x; b0 += u0.y;
        a1 += u1.x; b1 += u1.y;
        a2 += u2.x; b2 += u2.y;
        a3 += u3.x; b3 += u3.y;
    }
    for (; e < end; ++e) {
        float2 u = ((const float2*)&t2s[csr[e] * D2])[c];
        a0 += u.x; b0 += u.y;
    }
    float2 o;
    o.x = (a0 + a1) + (a2 + a3);
    o.y = (b0 + b1) + (b2 + b3);
    ((float2*)&acc2[wid * D2])[c] = o;
}

// ------- pool2: per-graph segmented reduce (batch is sorted) + fused FC ------
// block g: nodes [lb(g), lb(g+1)); thread t = channel; then out[g] = pm@Wfc+bfc
__global__ __launch_bounds__(128) void k_pool2(const float* __restrict__ acc2,
        const int* __restrict__ cnt_in, const float* __restrict__ b2,
        const int* __restrict__ batch, const float* __restrict__ Wfc,
        const float* __restrict__ bfc, float* __restrict__ out) {
    int g = blockIdx.x;
    int t = threadIdx.x;                 // 0..127 = channel
    // wave-uniform binary searches over sorted batch[]
    int lo = 0, hi = NN;
    while (lo < hi) { int mid = (lo + hi) >> 1; if (batch[mid] < g) lo = mid + 1; else hi = mid; }
    int beg = lo;
    hi = NN;
    while (lo < hi) { int mid = (lo + hi) >> 1; if (batch[mid] < g + 1) lo = mid + 1; else hi = mid; }
    int end = lo;

    float s0 = 0.0f, s1 = 0.0f;
    int i = beg;
    for (; i + 2 <= end; i += 2) {       // unroll x2 for load ILP
        float d0 = rsqrtf((float)cnt_in[i] + 1.0f);
        float d1 = rsqrtf((float)cnt_in[i + 1] + 1.0f);
        s0 += d0 * acc2[i * D2 + t];
        s1 += d1 * acc2[(i + 1) * D2 + t];
    }
    if (i < end)
        s0 += rsqrtf((float)cnt_in[i] + 1.0f) * acc2[i * D2 + t];

    int n = end - beg;
    // reference: pooled = (sum_i (dinv*acc2 + b2)) / max(n,1) = s/n + b2 (n>0), else 0
    float pooledv = (n > 0) ? ((s0 + s1) / (float)n + b2[t]) : 0.0f;

    __shared__ float pm[D2];
    pm[t] = pooledv;
    __syncthreads();
    if (t < HIDD) {
        float o = bfc[t];
        #pragma unroll
        for (int k = 0; k < D2; ++k)
            o += pm[k] * Wfc[k * HIDD + t];
        out[g * HIDD + t] = o;
    }
}

extern "C" void kernel_launch(void* const* d_in, const int* in_sizes, int n_in,
                              void* d_out, int out_size, void* d_ws, size_t ws_size,
                              hipStream_t stream) {
    const float* x     = (const float*)d_in[0];
    const int*   ei    = (const int*)  d_in[1];
    const int*   batch = (const int*)  d_in[2];
    const float* W1    = (const float*)d_in[3];
    const float* b1    = (const float*)d_in[4];
    const float* W2    = (const float*)d_in[5];
    const float* b2    = (const float*)d_in[6];
    const float* Wfc   = (const float*)d_in[7];
    const float* bfc   = (const float*)d_in[8];
    float* out = (float*)d_out;

    const int* src = ei;
    const int* dst = ei + EE;

    // ---- workspace layout ----
    float* fws    = (float*)d_ws;
    float* t1s    = fws;                        // NN*DD
    float* acc1   = t1s + NN * DD;              // NN*DD
    float* acc2   = t1s;                        // aliases t1s+acc1 (both dead)
    float* t2s    = acc1 + NN * DD;             // NN*D2
    int*   iws    = (int*)(t2s + NN * D2);
    int*   cnt_in = iws;                        // NN
    int*   rowptr = cnt_in + 50048;             // NN+1
    int*   cursor = rowptr + 50304;             // NN
    int*   part   = cursor + 50048;             // 256
    int*   csr    = part + 256;                 // EE
    // total ≈ 55 MB

    k_zero  <<<NBLK, 256, 0, stream>>>(cnt_in, part);
    k_count <<<(EE + 255) / 256, 256, 0, stream>>>(dst, cnt_in);
    k_partial<<<NBLK, 256, 0, stream>>>(cnt_in, part);
    k_scanp <<<1, 256, 0, stream>>>(part);
    k_rowptr<<<NBLK, 256, 0, stream>>>(cnt_in, part, rowptr, cursor);
    k_fill  <<<(EE + 255) / 256, 256, 0, stream>>>(src, dst, cursor, csr);
    k_gemm1 <<<(NN + 63) / 64, 256, 0, stream>>>(x, W1, cnt_in, t1s);
    k_agg1  <<<(NN * 64 + 255) / 256, 256, 0, stream>>>(rowptr, csr, t1s, acc1);
    k_gemm2 <<<(NN + 31) / 32, 256, 0, stream>>>(acc1, W2, b1, cnt_in, t2s);
    k_agg2  <<<(NN * 64 + 255) / 256, 256, 0, stream>>>(rowptr, csr, t2s, acc2);
    k_pool2 <<<GG, 128, 0, stream>>>(acc2, cnt_in, b2, batch, Wfc, bfc, out);
}